// Round 4
// baseline (79.981 us; speedup 1.0000x reference)
//
#include <hip/hip_runtime.h>

#define BATCH 4
#define SEQ   4096
#define EMB   1024
#define HD    64
#define NROW  (BATCH*SEQ)

typedef float f32x4  __attribute__((ext_vector_type(4)));
typedef short bf16x8 __attribute__((ext_vector_type(8)));
typedef short bf16x4 __attribute__((ext_vector_type(4)));

#define LOG2E 1.4426950408889634f

#if __has_builtin(__builtin_amdgcn_exp2f)
#define EXP2(x) __builtin_amdgcn_exp2f(x)
#else
#define EXP2(x) exp2f(x)
#endif

static __device__ __forceinline__ short f2bf(float f) {
  union { float f; unsigned u; } v; v.f = f;
  unsigned r = v.u + 0x7fffu + ((v.u >> 16) & 1u);
  return (short)(r >> 16);
}

static __device__ __forceinline__ unsigned cvtpk(float lo, float hi) {
  unsigned r;
  asm("v_cvt_pk_bf16_f32 %0, %1, %2" : "=v"(r) : "v"(lo), "v"(hi));
  return r;
}

// ---------------------------------------------------------------------------
// Wtf: fragment-contiguous B layout (unchanged from R3).
// ---------------------------------------------------------------------------
__global__ __launch_bounds__(256) void wt_kernel(
    const float* __restrict__ Wq, const float* __restrict__ Wk,
    const float* __restrict__ Wv, short* __restrict__ Wtf) {
  __shared__ float t[64][65];
  int bid = blockIdx.x;
  int mat = bid >> 4;
  int et  = bid & 15;
  int e0  = et * 64;
  const float* W = (mat == 0) ? Wq : (mat == 1) ? Wk : Wv;
  int c  = threadIdx.x & 63;
  int r0 = threadIdx.x >> 6;
#pragma unroll
  for (int i = 0; i < 16; ++i)
    t[i * 4 + r0][c] = W[(size_t)(e0 + i * 4 + r0) * HD + c];
  __syncthreads();
#pragma unroll
  for (int half = 0; half < 2; ++half) {
    int cid  = half * 256 + threadIdx.x;
    int ct4  = cid >> 7;
    int ksl  = (cid >> 6) & 1;
    int lane = cid & 63;
    int g    = lane >> 4;
    int mi   = lane & 15;
    int ct   = mat * 4 + ct4;
    int ks   = et * 2 + ksl;
    bf16x8 v;
#pragma unroll
    for (int j = 0; j < 8; ++j)
      v[j] = f2bf(t[ksl * 32 + 8 * g + j][ct4 * 16 + mi]);
    *(bf16x8*)(Wtf + ((size_t)(ct * 32 + ks) * 64 + lane) * 8) = v;
  }
}

// ---------------------------------------------------------------------------
// QKV projection (unchanged from R3).
// ---------------------------------------------------------------------------
__global__ __launch_bounds__(256) void qkv_kernel(
    const float* __restrict__ X, const short* __restrict__ Wtf,
    const float* __restrict__ bq, const float* __restrict__ bk, const float* __restrict__ bv,
    short* __restrict__ Qb, short* __restrict__ Kb, short* __restrict__ Vf) {
  __shared__ __align__(16) short xs[2][2][32][32];
  __shared__ float part[2][12][4][64];

  int tid  = threadIdx.x;
  int w    = tid >> 6;
  int lane = tid & 63;
  int g    = lane >> 4;
  int mi   = lane & 15;
  int rs   = w & 1;
  int h    = w >> 1;
  int rowbase = blockIdx.x * 32;

  int sr = tid >> 3;
  int sc = tid & 7;
  const float* xsrc = X + (size_t)(rowbase + sr) * EMB + sc * 4;

  f32x4 acc[12];
#pragma unroll
  for (int i = 0; i < 12; ++i) acc[i] = (f32x4){0.f, 0.f, 0.f, 0.f};

  {
    float4 xa = *(const float4*)(xsrc);
    float4 xb = *(const float4*)(xsrc + 512);
    bf16x4 va, vb;
    va[0] = f2bf(xa.x); va[1] = f2bf(xa.y); va[2] = f2bf(xa.z); va[3] = f2bf(xa.w);
    vb[0] = f2bf(xb.x); vb[1] = f2bf(xb.y); vb[2] = f2bf(xb.z); vb[3] = f2bf(xb.w);
    *(bf16x4*)(&xs[0][0][sr][sc * 4]) = va;
    *(bf16x4*)(&xs[0][1][sr][sc * 4]) = vb;
  }
  __syncthreads();

  const short* wp = Wtf + (size_t)(h * 16) * 512 + lane * 8;

#pragma unroll 2
  for (int ks = 0; ks < 16; ++ks) {
    int buf = ks & 1;
    float4 xa, xb;
    if (ks < 15) {
      xa = *(const float4*)(xsrc + (ks + 1) * 32);
      xb = *(const float4*)(xsrc + (ks + 1) * 32 + 512);
    }
    bf16x8 af = *(const bf16x8*)(&xs[buf][h][rs * 16 + mi][g * 8]);
    const short* wk = wp + ks * 512;
#pragma unroll
    for (int ct = 0; ct < 12; ++ct) {
      bf16x8 bfr = *(const bf16x8*)(wk + (size_t)ct * 16384);
      acc[ct] = __builtin_amdgcn_mfma_f32_16x16x32_bf16(af, bfr, acc[ct], 0, 0, 0);
    }
    if (ks < 15) {
      bf16x4 va, vb;
      va[0] = f2bf(xa.x); va[1] = f2bf(xa.y); va[2] = f2bf(xa.z); va[3] = f2bf(xa.w);
      vb[0] = f2bf(xb.x); vb[1] = f2bf(xb.y); vb[2] = f2bf(xb.z); vb[3] = f2bf(xb.w);
      *(bf16x4*)(&xs[buf ^ 1][0][sr][sc * 4]) = va;
      *(bf16x4*)(&xs[buf ^ 1][1][sr][sc * 4]) = vb;
    }
    __syncthreads();
  }

  if (h == 1) {
#pragma unroll
    for (int ct = 0; ct < 12; ++ct)
#pragma unroll
      for (int r = 0; r < 4; ++r) part[rs][ct][r][lane] = acc[ct][r];
  }
  __syncthreads();
  if (h == 0) {
#pragma unroll
    for (int ct = 0; ct < 12; ++ct)
#pragma unroll
      for (int r = 0; r < 4; ++r) part[rs][ct][r][lane] += acc[ct][r];
  }
  __syncthreads();

  {
    int row = tid >> 3;
    int c0  = (tid & 7) * 8;
    int rs2 = row >> 4, rr = row & 15, gg = rr >> 2, r2 = rr & 3;
    bf16x8 vq, vk;
#pragma unroll
    for (int j = 0; j < 8; ++j) {
      int col = c0 + j;
      vq[j] = f2bf(part[rs2][col >> 4][r2][gg * 16 + (col & 15)] + bq[col]);
      vk[j] = f2bf(part[rs2][4 + (col >> 4)][r2][gg * 16 + (col & 15)] + bk[col]);
    }
    *(bf16x8*)(Qb + (size_t)(rowbase + row) * HD + c0) = vq;
    *(bf16x8*)(Kb + (size_t)(rowbase + row) * HD + c0) = vk;
  }
  {
    int b   = rowbase >> 12;
    int c32 = (rowbase & (SEQ - 1)) >> 5;
    int gv  = tid >> 6;
    int hh  = tid & 63;
    int ht  = hh >> 4, mv = hh & 15;
    float bias = bv[hh];
    bf16x8 vv;
#pragma unroll
    for (int p = 0; p < 8; ++p) {
      int row = gv * 8 + p;
      int rs2 = row >> 4, rr = row & 15, gg = rr >> 2, r2 = rr & 3;
      vv[p] = f2bf(part[rs2][8 + ht][r2][gg * 16 + mv] + bias);
    }
    *(bf16x8*)(Vf + ((size_t)((b * 128 + c32) * 4 + ht)) * 512 + (gv * 16 + mv) * 8) = vv;
  }
}

// ---------------------------------------------------------------------------
// Flash attention: KVBLK=64, log2-domain softmax, cvt_pk packing, deferred-PV
// pipeline (PV of block b-1 overlaps scores of block b), defer-max skip,
// mask only in final 64-block, padded p_lds (2-way max).
// ---------------------------------------------------------------------------
__global__ __launch_bounds__(256, 2) void attn_kernel(
    const short* __restrict__ Qb, const short* __restrict__ Kb,
    const short* __restrict__ Vf, float* __restrict__ out) {
  __shared__ float lds_o[4][64][16];
  __shared__ float lds_m[4][16];
  __shared__ float lds_l[4][16];
  __shared__ __align__(16) short p_lds[4][2][16][72];   // padded rows (2-way)

  int tid  = threadIdx.x;
  int w    = tid >> 6;
  int lane = tid & 63;
  int g    = lane >> 4;
  int qi   = lane & 15;
  int batch = blockIdx.x >> 7;
  int jj    = blockIdx.x & 127;

  const short* vbase = Vf + (size_t)batch * 128 * 4 * 512;
  const float K1 = 0.125f * LOG2E;   // fold 1/sqrt(64) and log2(e)

  for (int ph = 0; ph < 2; ++ph) {
    int t  = ph ? (255 - jj) : jj;
    int q0 = t * 16;
    int row = q0 + qi;

    const short* qptr = Qb + ((size_t)(batch * SEQ + row)) * HD + 8 * g;
    bf16x8 qf0 = *(const bf16x8*)(qptr);
    bf16x8 qf1 = *(const bf16x8*)(qptr + 32);

    int C = t + 1;
    int total64 = (C + 3) >> 2;
    int blo = (w * total64) >> 2;
    int bhi = ((w + 1) * total64) >> 2;

    float m2 = -INFINITY, lsum = 0.f;
    float aprev = 1.f;
    int bprev = -1, pbuf = 0;
    bool growPrev = false;
    f32x4 o[4];
#pragma unroll
    for (int i = 0; i < 4; ++i) o[i] = (f32x4){0.f, 0.f, 0.f, 0.f};

    for (int b = blo; b < bhi; ++b) {
      int kv0 = b * 64;
      // ---- QK^T for 64 kv ----
      f32x4 z[4];
#pragma unroll
      for (int ca = 0; ca < 4; ++ca) {
        const short* kptr = Kb + ((size_t)(batch * SEQ + kv0 + ca * 16 + qi)) * HD + 8 * g;
        bf16x8 kf0 = *(const bf16x8*)(kptr);
        bf16x8 kf1 = *(const bf16x8*)(kptr + 32);
        f32x4 zz = (f32x4){0.f, 0.f, 0.f, 0.f};
        zz = __builtin_amdgcn_mfma_f32_16x16x32_bf16(kf0, qf0, zz, 0, 0, 0);
        zz = __builtin_amdgcn_mfma_f32_16x16x32_bf16(kf1, qf1, zz, 0, 0, 0);
        z[ca] = zz;
      }
      if (kv0 + 63 >= q0) {   // only final block needs causal mask
#pragma unroll
        for (int ca = 0; ca < 4; ++ca)
#pragma unroll
          for (int r = 0; r < 4; ++r) {
            int col = kv0 + ca * 16 + 4 * g + r;
            z[ca][r] = (col <= row) ? z[ca][r] : -INFINITY;
          }
      }
      // ---- max + defer test ----
      float mx = fmaxf(fmaxf(fmaxf(z[0][0], z[0][1]), fmaxf(z[0][2], z[0][3])),
                       fmaxf(fmaxf(z[1][0], z[1][1]), fmaxf(z[1][2], z[1][3])));
      mx = fmaxf(mx, fmaxf(fmaxf(fmaxf(z[2][0], z[2][1]), fmaxf(z[2][2], z[2][3])),
                           fmaxf(fmaxf(z[3][0], z[3][1]), fmaxf(z[3][2], z[3][3]))));
      mx = fmaxf(mx, __shfl_xor(mx, 16));
      mx = fmaxf(mx, __shfl_xor(mx, 32));
      float pmax2 = mx * K1;
      bool grow = __any(pmax2 > m2);
      float alpha = 1.f;
      if (grow) {
        float m2n = fmaxf(m2, pmax2);
        alpha = EXP2(m2 - m2n);
        m2 = m2n;
      }
      // ---- P = exp2(z*K1 - m2), sum, pack, store ----
      float sum = 0.f;
#pragma unroll
      for (int ca = 0; ca < 4; ++ca) {
        float p0 = EXP2(fmaf(z[ca][0], K1, -m2));
        float p1 = EXP2(fmaf(z[ca][1], K1, -m2));
        float p2 = EXP2(fmaf(z[ca][2], K1, -m2));
        float p3 = EXP2(fmaf(z[ca][3], K1, -m2));
        sum += (p0 + p1) + (p2 + p3);
        unsigned w0 = cvtpk(p0, p1);
        unsigned w1 = cvtpk(p2, p3);
        *(uint2*)(&p_lds[w][pbuf][qi][ca * 16 + 4 * g]) = make_uint2(w0, w1);
      }
      sum += __shfl_xor(sum, 16);
      sum += __shfl_xor(sum, 32);
      lsum = grow ? fmaf(lsum, alpha, sum) : (lsum + sum);
      // ---- PV of PREVIOUS block (LDS write->read distance = 1 iteration) ----
      if (bprev >= 0) {
        if (growPrev) {
#pragma unroll
          for (int i = 0; i < 4; ++i) {
            o[i][0] *= aprev; o[i][1] *= aprev; o[i][2] *= aprev; o[i][3] *= aprev;
          }
        }
        bf16x8 pf0 = *(const bf16x8*)(&p_lds[w][pbuf ^ 1][qi][8 * g]);
        bf16x8 pf1 = *(const bf16x8*)(&p_lds[w][pbuf ^ 1][qi][32 + 8 * g]);
        const short* vp = vbase + ((size_t)(2 * bprev) * 4) * 512 + lane * 8;
#pragma unroll
        for (int ht = 0; ht < 4; ++ht)
          o[ht] = __builtin_amdgcn_mfma_f32_16x16x32_bf16(
              *(const bf16x8*)(vp + ht * 512), pf0, o[ht], 0, 0, 0);
#pragma unroll
        for (int ht = 0; ht < 4; ++ht)
          o[ht] = __builtin_amdgcn_mfma_f32_16x16x32_bf16(
              *(const bf16x8*)(vp + (4 + ht) * 512), pf1, o[ht], 0, 0, 0);
      }
      aprev = alpha;
      growPrev = grow;
      bprev = b;
      pbuf ^= 1;
    }
    // ---- epilogue PV of last block ----
    if (bprev >= 0) {
      if (growPrev) {
#pragma unroll
        for (int i = 0; i < 4; ++i) {
          o[i][0] *= aprev; o[i][1] *= aprev; o[i][2] *= aprev; o[i][3] *= aprev;
        }
      }
      bf16x8 pf0 = *(const bf16x8*)(&p_lds[w][pbuf ^ 1][qi][8 * g]);
      bf16x8 pf1 = *(const bf16x8*)(&p_lds[w][pbuf ^ 1][qi][32 + 8 * g]);
      const short* vp = vbase + ((size_t)(2 * bprev) * 4) * 512 + lane * 8;
#pragma unroll
      for (int ht = 0; ht < 4; ++ht)
        o[ht] = __builtin_amdgcn_mfma_f32_16x16x32_bf16(
            *(const bf16x8*)(vp + ht * 512), pf0, o[ht], 0, 0, 0);
#pragma unroll
      for (int ht = 0; ht < 4; ++ht)
        o[ht] = __builtin_amdgcn_mfma_f32_16x16x32_bf16(
            *(const bf16x8*)(vp + (4 + ht) * 512), pf1, o[ht], 0, 0, 0);
    }

    // ---- cross-wave flash combine ----
#pragma unroll
    for (int ht = 0; ht < 4; ++ht)
#pragma unroll
      for (int r = 0; r < 4; ++r)
        lds_o[w][ht * 16 + 4 * g + r][qi] = o[ht][r];
    if (lane < 16) { lds_m[w][lane] = m2; lds_l[w][lane] = lsum; }
    __syncthreads();

    {
      int q  = tid & 15;
      int hb = (tid >> 4) * 4;
      float m0 = lds_m[0][q], m1 = lds_m[1][q], m2c = lds_m[2][q], m3 = lds_m[3][q];
      float mm = fmaxf(fmaxf(m0, m1), fmaxf(m2c, m3));
      float e0 = EXP2(m0 - mm);
      float e1 = EXP2(m1 - mm);
      float e2 = EXP2(m2c - mm);
      float e3 = EXP2(m3 - mm);
      float denom = lds_l[0][q] * e0 + lds_l[1][q] * e1 + lds_l[2][q] * e2 + lds_l[3][q] * e3;
      float inv = 1.f / denom;
      f32x4 res;
#pragma unroll
      for (int i = 0; i < 4; ++i) {
        res[i] = (e0 * lds_o[0][hb + i][q] + e1 * lds_o[1][hb + i][q] +
                  e2 * lds_o[2][hb + i][q] + e3 * lds_o[3][hb + i][q]) * inv;
      }
      *(f32x4*)(out + ((size_t)(batch * SEQ + q0 + q)) * HD + hb) = res;
    }
    __syncthreads();
  }
}

// ---------------------------------------------------------------------------
extern "C" void kernel_launch(void* const* d_in, const int* in_sizes, int n_in,
                              void* d_out, int out_size, void* d_ws, size_t ws_size,
                              hipStream_t stream) {
  const float* X  = (const float*)d_in[0];
  const float* Wq = (const float*)d_in[1];
  const float* bq = (const float*)d_in[2];
  const float* Wk = (const float*)d_in[3];
  const float* bk = (const float*)d_in[4];
  const float* Wv = (const float*)d_in[5];
  const float* bv = (const float*)d_in[6];
  float* out = (float*)d_out;

  char* ws = (char*)d_ws;
  const size_t SZ = (size_t)NROW * HD * 2;
  short* Qb  = (short*)(ws);
  short* Kb  = (short*)(ws + SZ);
  short* Vf  = (short*)(ws + 2 * SZ);
  short* Wtf = (short*)(ws + 3 * SZ);

  wt_kernel<<<48, 256, 0, stream>>>(Wq, Wk, Wv, Wtf);
  qkv_kernel<<<NROW / 32, 256, 0, stream>>>(X, Wtf, bq, bk, bv, Qb, Kb, Vf);
  attn_kernel<<<BATCH * 128, 256, 0, stream>>>(Qb, Kb, Vf, out);
}

// Round 5
// 75.189 us; speedup vs baseline: 1.0637x; 1.0637x over previous
//
#include <hip/hip_runtime.h>

#define BATCH 4
#define SEQ   4096
#define EMB   1024
#define HD    64
#define NROW  (BATCH*SEQ)

typedef float f32x4  __attribute__((ext_vector_type(4)));
typedef short bf16x8 __attribute__((ext_vector_type(8)));
typedef short bf16x4 __attribute__((ext_vector_type(4)));

#define LOG2E 1.4426950408889634f
#define EXP2(x) exp2f(x)

static __device__ __forceinline__ short f2bf(float f) {
  union { float f; unsigned u; } v; v.f = f;
  unsigned r = v.u + 0x7fffu + ((v.u >> 16) & 1u);
  return (short)(r >> 16);
}
static __device__ __forceinline__ float bf2f(short s) {
  union { unsigned u; float f; } v; v.u = ((unsigned)(unsigned short)s) << 16;
  return v.f;
}
static __device__ __forceinline__ unsigned cvtpk(float lo, float hi) {
  unsigned r;
  asm("v_cvt_pk_bf16_f32 %0, %1, %2" : "=v"(r) : "v"(lo), "v"(hi));
  return r;
}
static __device__ __forceinline__ float max3f(float a, float b, float c) {
  float r;
  asm("v_max3_f32 %0, %1, %2, %3" : "=v"(r) : "v"(a), "v"(b), "v"(c));
  return r;
}

// ---------------------------------------------------------------------------
// Wtf: fragment-contiguous B layout (unchanged).
// ---------------------------------------------------------------------------
__global__ __launch_bounds__(256) void wt_kernel(
    const float* __restrict__ Wq, const float* __restrict__ Wk,
    const float* __restrict__ Wv, short* __restrict__ Wtf) {
  __shared__ float t[64][65];
  int bid = blockIdx.x;
  int mat = bid >> 4;
  int et  = bid & 15;
  int e0  = et * 64;
  const float* W = (mat == 0) ? Wq : (mat == 1) ? Wk : Wv;
  int c  = threadIdx.x & 63;
  int r0 = threadIdx.x >> 6;
#pragma unroll
  for (int i = 0; i < 16; ++i)
    t[i * 4 + r0][c] = W[(size_t)(e0 + i * 4 + r0) * HD + c];
  __syncthreads();
#pragma unroll
  for (int half = 0; half < 2; ++half) {
    int cid  = half * 256 + threadIdx.x;
    int ct4  = cid >> 7;
    int ksl  = (cid >> 6) & 1;
    int lane = cid & 63;
    int g    = lane >> 4;
    int mi   = lane & 15;
    int ct   = mat * 4 + ct4;
    int ks   = et * 2 + ksl;
    bf16x8 v;
#pragma unroll
    for (int j = 0; j < 8; ++j)
      v[j] = f2bf(t[ksl * 32 + 8 * g + j][ct4 * 16 + mi]);
    *(bf16x8*)(Wtf + ((size_t)(ct * 32 + ks) * 64 + lane) * 8) = v;
  }
}

// ---------------------------------------------------------------------------
// QKV projection (unchanged from R3).
// ---------------------------------------------------------------------------
__global__ __launch_bounds__(256) void qkv_kernel(
    const float* __restrict__ X, const short* __restrict__ Wtf,
    const float* __restrict__ bq, const float* __restrict__ bk, const float* __restrict__ bv,
    short* __restrict__ Qb, short* __restrict__ Kb, short* __restrict__ Vf) {
  __shared__ __align__(16) short xs[2][2][32][32];
  __shared__ float part[2][12][4][64];

  int tid  = threadIdx.x;
  int w    = tid >> 6;
  int lane = tid & 63;
  int g    = lane >> 4;
  int mi   = lane & 15;
  int rs   = w & 1;
  int h    = w >> 1;
  int rowbase = blockIdx.x * 32;

  int sr = tid >> 3;
  int sc = tid & 7;
  const float* xsrc = X + (size_t)(rowbase + sr) * EMB + sc * 4;

  f32x4 acc[12];
#pragma unroll
  for (int i = 0; i < 12; ++i) acc[i] = (f32x4){0.f, 0.f, 0.f, 0.f};

  {
    float4 xa = *(const float4*)(xsrc);
    float4 xb = *(const float4*)(xsrc + 512);
    bf16x4 va, vb;
    va[0] = f2bf(xa.x); va[1] = f2bf(xa.y); va[2] = f2bf(xa.z); va[3] = f2bf(xa.w);
    vb[0] = f2bf(xb.x); vb[1] = f2bf(xb.y); vb[2] = f2bf(xb.z); vb[3] = f2bf(xb.w);
    *(bf16x4*)(&xs[0][0][sr][sc * 4]) = va;
    *(bf16x4*)(&xs[0][1][sr][sc * 4]) = vb;
  }
  __syncthreads();

  const short* wp = Wtf + (size_t)(h * 16) * 512 + lane * 8;

#pragma unroll 2
  for (int ks = 0; ks < 16; ++ks) {
    int buf = ks & 1;
    float4 xa, xb;
    if (ks < 15) {
      xa = *(const float4*)(xsrc + (ks + 1) * 32);
      xb = *(const float4*)(xsrc + (ks + 1) * 32 + 512);
    }
    bf16x8 af = *(const bf16x8*)(&xs[buf][h][rs * 16 + mi][g * 8]);
    const short* wk = wp + ks * 512;
#pragma unroll
    for (int ct = 0; ct < 12; ++ct) {
      bf16x8 bfr = *(const bf16x8*)(wk + (size_t)ct * 16384);
      acc[ct] = __builtin_amdgcn_mfma_f32_16x16x32_bf16(af, bfr, acc[ct], 0, 0, 0);
    }
    if (ks < 15) {
      bf16x4 va, vb;
      va[0] = f2bf(xa.x); va[1] = f2bf(xa.y); va[2] = f2bf(xa.z); va[3] = f2bf(xa.w);
      vb[0] = f2bf(xb.x); vb[1] = f2bf(xb.y); vb[2] = f2bf(xb.z); vb[3] = f2bf(xb.w);
      *(bf16x4*)(&xs[buf ^ 1][0][sr][sc * 4]) = va;
      *(bf16x4*)(&xs[buf ^ 1][1][sr][sc * 4]) = vb;
    }
    __syncthreads();
  }

  if (h == 1) {
#pragma unroll
    for (int ct = 0; ct < 12; ++ct)
#pragma unroll
      for (int r = 0; r < 4; ++r) part[rs][ct][r][lane] = acc[ct][r];
  }
  __syncthreads();
  if (h == 0) {
#pragma unroll
    for (int ct = 0; ct < 12; ++ct)
#pragma unroll
      for (int r = 0; r < 4; ++r) part[rs][ct][r][lane] += acc[ct][r];
  }
  __syncthreads();

  {
    int row = tid >> 3;
    int c0  = (tid & 7) * 8;
    int rs2 = row >> 4, rr = row & 15, gg = rr >> 2, r2 = rr & 3;
    bf16x8 vq, vk;
#pragma unroll
    for (int j = 0; j < 8; ++j) {
      int col = c0 + j;
      vq[j] = f2bf(part[rs2][col >> 4][r2][gg * 16 + (col & 15)] + bq[col]);
      vk[j] = f2bf(part[rs2][4 + (col >> 4)][r2][gg * 16 + (col & 15)] + bk[col]);
    }
    *(bf16x8*)(Qb + (size_t)(rowbase + row) * HD + c0) = vq;
    *(bf16x8*)(Kb + (size_t)(rowbase + row) * HD + c0) = vk;
  }
  {
    int b   = rowbase >> 12;
    int c32 = (rowbase & (SEQ - 1)) >> 5;
    int gv  = tid >> 6;
    int hh  = tid & 63;
    int ht  = hh >> 4, mv = hh & 15;
    float bias = bv[hh];
    bf16x8 vv;
#pragma unroll
    for (int p = 0; p < 8; ++p) {
      int row = gv * 8 + p;
      int rs2 = row >> 4, rr = row & 15, gg = rr >> 2, r2 = rr & 3;
      vv[p] = f2bf(part[rs2][8 + ht][r2][gg * 16 + mv] + bias);
    }
    *(bf16x8*)(Vf + ((size_t)((b * 128 + c32) * 4 + ht)) * 512 + (gv * 16 + mv) * 8) = vv;
  }
}

// ---------------------------------------------------------------------------
// Flash attention: 8 waves/block (512 thr), kv split 8-way, PV-before-QK
// latency overlap, lazy cross-lane reductions, defer-max, setprio.
// ---------------------------------------------------------------------------
__global__ __launch_bounds__(512, 4) void attn_kernel(
    const short* __restrict__ Qb, const short* __restrict__ Kb,
    const short* __restrict__ Vf, float* __restrict__ out) {
  __shared__ short lds_o[8][64][17];                    // bf16 partial O, 17.4 KB
  __shared__ float lds_m[8][16];
  __shared__ float lds_l[8][16];
  __shared__ __align__(16) short p_lds[8][2][16][68];   // 34.8 KB

  int tid  = threadIdx.x;
  int w    = tid >> 6;        // 0..7
  int lane = tid & 63;
  int g    = lane >> 4;
  int qi   = lane & 15;
  int batch = blockIdx.x >> 7;
  int jj    = blockIdx.x & 127;

  const short* vbase = Vf + (size_t)batch * 128 * 4 * 512;
  const float K1 = 0.125f * LOG2E;

  for (int ph = 0; ph < 2; ++ph) {
    int t  = ph ? (255 - jj) : jj;
    int q0 = t * 16;
    int row = q0 + qi;

    const short* qptr = Qb + ((size_t)(batch * SEQ + row)) * HD + 8 * g;
    bf16x8 qf0 = *(const bf16x8*)(qptr);
    bf16x8 qf1 = *(const bf16x8*)(qptr + 32);

    int C = t + 1;
    int total64 = (C + 3) >> 2;
    int blo = (w * total64) >> 3;
    int bhi = ((w + 1) * total64) >> 3;

    float m2 = -INFINITY, lsum = 0.f;
    float aprev = 1.f;
    bool growPrev = false;
    int pbuf = 0;
    f32x4 o[4];
#pragma unroll
    for (int i = 0; i < 4; ++i) o[i] = (f32x4){0.f, 0.f, 0.f, 0.f};

    for (int b = blo; b < bhi; ++b) {
      int kv0 = b * 64;
      // --- issue K loads for this block ---
      const short* kp = Kb + ((size_t)(batch * SEQ + kv0 + qi)) * HD + 8 * g;
      bf16x8 kf[4][2];
#pragma unroll
      for (int ca = 0; ca < 4; ++ca) {
        kf[ca][0] = *(const bf16x8*)(kp + (size_t)ca * 16 * HD);
        kf[ca][1] = *(const bf16x8*)(kp + (size_t)ca * 16 * HD + 32);
      }
      // --- issue V loads + PV for previous block (overlaps K latency) ---
      if (b > blo) {
        bf16x8 vr[8];
        const short* vp = vbase + ((size_t)(2 * (b - 1)) * 4) * 512 + lane * 8;
#pragma unroll
        for (int i = 0; i < 8; ++i) vr[i] = *(const bf16x8*)(vp + i * 512);
        if (growPrev) {
#pragma unroll
          for (int i = 0; i < 4; ++i) {
            o[i][0] *= aprev; o[i][1] *= aprev; o[i][2] *= aprev; o[i][3] *= aprev;
          }
        }
        bf16x8 pf0 = *(const bf16x8*)(&p_lds[w][pbuf ^ 1][qi][8 * g]);
        bf16x8 pf1 = *(const bf16x8*)(&p_lds[w][pbuf ^ 1][qi][32 + 8 * g]);
        __builtin_amdgcn_s_setprio(1);
#pragma unroll
        for (int ht = 0; ht < 4; ++ht)
          o[ht] = __builtin_amdgcn_mfma_f32_16x16x32_bf16(vr[ht], pf0, o[ht], 0, 0, 0);
#pragma unroll
        for (int ht = 0; ht < 4; ++ht)
          o[ht] = __builtin_amdgcn_mfma_f32_16x16x32_bf16(vr[4 + ht], pf1, o[ht], 0, 0, 0);
        __builtin_amdgcn_s_setprio(0);
      }
      // --- QK^T ---
      f32x4 z[4];
      __builtin_amdgcn_s_setprio(1);
#pragma unroll
      for (int ca = 0; ca < 4; ++ca) {
        f32x4 zz = (f32x4){0.f, 0.f, 0.f, 0.f};
        zz = __builtin_amdgcn_mfma_f32_16x16x32_bf16(kf[ca][0], qf0, zz, 0, 0, 0);
        zz = __builtin_amdgcn_mfma_f32_16x16x32_bf16(kf[ca][1], qf1, zz, 0, 0, 0);
        z[ca] = zz;
      }
      __builtin_amdgcn_s_setprio(0);
      if (kv0 + 63 >= q0) {
#pragma unroll
        for (int ca = 0; ca < 4; ++ca)
#pragma unroll
          for (int r = 0; r < 4; ++r) {
            int col = kv0 + ca * 16 + 4 * g + r;
            z[ca][r] = (col <= row) ? z[ca][r] : -INFINITY;
          }
      }
      // --- lazy max: cross-lane reduce only when a lane's local max grows ---
      float t1 = max3f(z[0][0], z[0][1], z[0][2]);
      float t2 = max3f(z[0][3], z[1][0], z[1][1]);
      float t3 = max3f(z[1][2], z[1][3], z[2][0]);
      float t4 = max3f(z[2][1], z[2][2], z[2][3]);
      float t5 = max3f(z[3][0], z[3][1], z[3][2]);
      float lmax = fmaxf(max3f(t1, t2, t3), max3f(t4, t5, z[3][3]));
      bool grow = __any(lmax * K1 > m2);
      float alpha = 1.f;
      if (grow) {
        float gm = fmaxf(lmax, __shfl_xor(lmax, 16));
        gm = fmaxf(gm, __shfl_xor(gm, 32));
        float m2n = fmaxf(m2, gm * K1);
        alpha = EXP2(m2 - m2n);
        m2 = m2n;
      }
      // --- P = exp2(z*K1 - m2), per-lane sum, pack, store ---
      float ls = 0.f;
#pragma unroll
      for (int ca = 0; ca < 4; ++ca) {
        float p0 = EXP2(fmaf(z[ca][0], K1, -m2));
        float p1 = EXP2(fmaf(z[ca][1], K1, -m2));
        float p2 = EXP2(fmaf(z[ca][2], K1, -m2));
        float p3 = EXP2(fmaf(z[ca][3], K1, -m2));
        ls += (p0 + p1) + (p2 + p3);
        unsigned w0 = cvtpk(p0, p1);
        unsigned w1 = cvtpk(p2, p3);
        *(uint2*)(&p_lds[w][pbuf][qi][ca * 16 + 4 * g]) = make_uint2(w0, w1);
      }
      lsum = grow ? fmaf(lsum, alpha, ls) : (lsum + ls);
      aprev = alpha;
      growPrev = grow;
      pbuf ^= 1;
    }
    // --- epilogue PV of last block ---
    if (bhi > blo) {
      int bl = bhi - 1;
      bf16x8 vr[8];
      const short* vp = vbase + ((size_t)(2 * bl) * 4) * 512 + lane * 8;
#pragma unroll
      for (int i = 0; i < 8; ++i) vr[i] = *(const bf16x8*)(vp + i * 512);
      if (growPrev) {
#pragma unroll
        for (int i = 0; i < 4; ++i) {
          o[i][0] *= aprev; o[i][1] *= aprev; o[i][2] *= aprev; o[i][3] *= aprev;
        }
      }
      bf16x8 pf0 = *(const bf16x8*)(&p_lds[w][pbuf ^ 1][qi][8 * g]);
      bf16x8 pf1 = *(const bf16x8*)(&p_lds[w][pbuf ^ 1][qi][32 + 8 * g]);
      __builtin_amdgcn_s_setprio(1);
#pragma unroll
      for (int ht = 0; ht < 4; ++ht)
        o[ht] = __builtin_amdgcn_mfma_f32_16x16x32_bf16(vr[ht], pf0, o[ht], 0, 0, 0);
#pragma unroll
      for (int ht = 0; ht < 4; ++ht)
        o[ht] = __builtin_amdgcn_mfma_f32_16x16x32_bf16(vr[4 + ht], pf1, o[ht], 0, 0, 0);
      __builtin_amdgcn_s_setprio(0);
    }

    // --- cross-wave flash combine (8 waves) ---
    lsum += __shfl_xor(lsum, 16);
    lsum += __shfl_xor(lsum, 32);
#pragma unroll
    for (int ht = 0; ht < 4; ++ht)
#pragma unroll
      for (int r = 0; r < 4; ++r)
        lds_o[w][ht * 16 + 4 * g + r][qi] = f2bf(o[ht][r]);
    if (lane < 16) { lds_m[w][lane] = m2; lds_l[w][lane] = lsum; }
    __syncthreads();

    {
      int q  = tid >> 5;          // 0..15
      int c2 = tid & 31;          // 0..31
      int hb = c2 * 2;
      float mm = lds_m[0][q];
#pragma unroll
      for (int wv = 1; wv < 8; ++wv) mm = fmaxf(mm, lds_m[wv][q]);
      float denom = 0.f, a0 = 0.f, a1 = 0.f;
#pragma unroll
      for (int wv = 0; wv < 8; ++wv) {
        float e = EXP2(lds_m[wv][q] - mm);
        denom += lds_l[wv][q] * e;
        a0 += e * bf2f(lds_o[wv][hb][q]);
        a1 += e * bf2f(lds_o[wv][hb + 1][q]);
      }
      float inv = 1.f / denom;
      float2 res = make_float2(a0 * inv, a1 * inv);
      *(float2*)(out + ((size_t)(batch * SEQ + q0 + q)) * HD + hb) = res;
    }
    __syncthreads();
  }
}

// ---------------------------------------------------------------------------
extern "C" void kernel_launch(void* const* d_in, const int* in_sizes, int n_in,
                              void* d_out, int out_size, void* d_ws, size_t ws_size,
                              hipStream_t stream) {
  const float* X  = (const float*)d_in[0];
  const float* Wq = (const float*)d_in[1];
  const float* bq = (const float*)d_in[2];
  const float* Wk = (const float*)d_in[3];
  const float* bk = (const float*)d_in[4];
  const float* Wv = (const float*)d_in[5];
  const float* bv = (const float*)d_in[6];
  float* out = (float*)d_out;

  char* ws = (char*)d_ws;
  const size_t SZ = (size_t)NROW * HD * 2;
  short* Qb  = (short*)(ws);
  short* Kb  = (short*)(ws + SZ);
  short* Vf  = (short*)(ws + 2 * SZ);
  short* Wtf = (short*)(ws + 3 * SZ);

  wt_kernel<<<48, 256, 0, stream>>>(Wq, Wk, Wv, Wtf);
  qkv_kernel<<<NROW / 32, 256, 0, stream>>>(X, Wtf, bq, bk, bv, Qb, Kb, Vf);
  attn_kernel<<<BATCH * 128, 512, 0, stream>>>(Qb, Kb, Vf, out);
}

// Round 7
// 56.474 us; speedup vs baseline: 1.4162x; 1.3314x over previous
//
#include <hip/hip_runtime.h>

#define BATCH 4
#define SEQ   4096
#define EMB   1024
#define HD    64
#define NROW  (BATCH*SEQ)

typedef float f32x4  __attribute__((ext_vector_type(4)));
typedef short bf16x8 __attribute__((ext_vector_type(8)));
typedef short bf16x4 __attribute__((ext_vector_type(4)));

#define LOG2E 1.4426950408889634f
#define EXP2(x) exp2f(x)

static __device__ __forceinline__ f32x4 MFMA16(bf16x4 a, bf16x4 b, f32x4 c) {
#if defined(__HIP_DEVICE_COMPILE__) && __has_builtin(__builtin_amdgcn_mfma_f32_16x16x16bf16_1k)
  return __builtin_amdgcn_mfma_f32_16x16x16bf16_1k(a, b, c, 0, 0, 0);
#elif defined(__HIP_DEVICE_COMPILE__)
  f32x4 d;
  asm volatile("v_mfma_f32_16x16x16_bf16 %0, %1, %2, %3"
               : "=v"(d) : "v"(a), "v"(b), "v"(c));
  return d;
#else
  return c;  // host stub, never executed
#endif
}

static __device__ __forceinline__ short f2bf(float f) {
  union { float f; unsigned u; } v; v.f = f;
  unsigned r = v.u + 0x7fffu + ((v.u >> 16) & 1u);
  return (short)(r >> 16);
}
static __device__ __forceinline__ float bf2f(short s) {
  union { unsigned u; float f; } v; v.u = ((unsigned)(unsigned short)s) << 16;
  return v.f;
}
static __device__ __forceinline__ unsigned cvtpk(float lo, float hi) {
  unsigned r;
  asm("v_cvt_pk_bf16_f32 %0, %1, %2" : "=v"(r) : "v"(lo), "v"(hi));
  return r;
}
static __device__ __forceinline__ float max3f(float a, float b, float c) {
  float r;
  asm("v_max3_f32 %0, %1, %2, %3" : "=v"(r) : "v"(a), "v"(b), "v"(c));
  return r;
}
static __device__ __forceinline__ bf16x4 pack4(unsigned w01, unsigned w23) {
  union { unsigned u[2]; bf16x4 v; } x;
  x.u[0] = w01; x.u[1] = w23;
  return x.v;
}

// ---------------------------------------------------------------------------
// Wtf: fragment-contiguous B layout (unchanged).
// ---------------------------------------------------------------------------
__global__ __launch_bounds__(256) void wt_kernel(
    const float* __restrict__ Wq, const float* __restrict__ Wk,
    const float* __restrict__ Wv, short* __restrict__ Wtf) {
  __shared__ float t[64][65];
  int bid = blockIdx.x;
  int mat = bid >> 4;
  int et  = bid & 15;
  int e0  = et * 64;
  const float* W = (mat == 0) ? Wq : (mat == 1) ? Wk : Wv;
  int c  = threadIdx.x & 63;
  int r0 = threadIdx.x >> 6;
#pragma unroll
  for (int i = 0; i < 16; ++i)
    t[i * 4 + r0][c] = W[(size_t)(e0 + i * 4 + r0) * HD + c];
  __syncthreads();
#pragma unroll
  for (int half = 0; half < 2; ++half) {
    int cid  = half * 256 + threadIdx.x;
    int ct4  = cid >> 7;
    int ksl  = (cid >> 6) & 1;
    int lane = cid & 63;
    int g    = lane >> 4;
    int mi   = lane & 15;
    int ct   = mat * 4 + ct4;
    int ks   = et * 2 + ksl;
    bf16x8 v;
#pragma unroll
    for (int j = 0; j < 8; ++j)
      v[j] = f2bf(t[ksl * 32 + 8 * g + j][ct4 * 16 + mi]);
    *(bf16x8*)(Wtf + ((size_t)(ct * 32 + ks) * 64 + lane) * 8) = v;
  }
}

// ---------------------------------------------------------------------------
// QKV projection. Main loop unchanged; epilogue writes fragment-packed
// Qf/Kf (1KB chunk per (tile,kh)) and Vf (1KB chunk per (c32,ht)).
// ---------------------------------------------------------------------------
__global__ __launch_bounds__(256) void qkv_kernel(
    const float* __restrict__ X, const short* __restrict__ Wtf,
    const float* __restrict__ bq, const float* __restrict__ bk, const float* __restrict__ bv,
    short* __restrict__ Qf, short* __restrict__ Kf, short* __restrict__ Vf) {
  __shared__ __align__(16) short xs[2][2][32][32];
  __shared__ float part[2][12][4][64];

  int tid  = threadIdx.x;
  int w    = tid >> 6;
  int lane = tid & 63;
  int g    = lane >> 4;
  int mi   = lane & 15;
  int rs   = w & 1;
  int h    = w >> 1;
  int rowbase = blockIdx.x * 32;

  int sr = tid >> 3;
  int sc = tid & 7;
  const float* xsrc = X + (size_t)(rowbase + sr) * EMB + sc * 4;

  f32x4 acc[12];
#pragma unroll
  for (int i = 0; i < 12; ++i) acc[i] = (f32x4){0.f, 0.f, 0.f, 0.f};

  {
    float4 xa = *(const float4*)(xsrc);
    float4 xb = *(const float4*)(xsrc + 512);
    bf16x4 va, vb;
    va[0] = f2bf(xa.x); va[1] = f2bf(xa.y); va[2] = f2bf(xa.z); va[3] = f2bf(xa.w);
    vb[0] = f2bf(xb.x); vb[1] = f2bf(xb.y); vb[2] = f2bf(xb.z); vb[3] = f2bf(xb.w);
    *(bf16x4*)(&xs[0][0][sr][sc * 4]) = va;
    *(bf16x4*)(&xs[0][1][sr][sc * 4]) = vb;
  }
  __syncthreads();

  const short* wp = Wtf + (size_t)(h * 16) * 512 + lane * 8;

#pragma unroll 2
  for (int ks = 0; ks < 16; ++ks) {
    int buf = ks & 1;
    float4 xa, xb;
    if (ks < 15) {
      xa = *(const float4*)(xsrc + (ks + 1) * 32);
      xb = *(const float4*)(xsrc + (ks + 1) * 32 + 512);
    }
    bf16x8 af = *(const bf16x8*)(&xs[buf][h][rs * 16 + mi][g * 8]);
    const short* wk = wp + ks * 512;
#pragma unroll
    for (int ct = 0; ct < 12; ++ct) {
      bf16x8 bfr = *(const bf16x8*)(wk + (size_t)ct * 16384);
      acc[ct] = __builtin_amdgcn_mfma_f32_16x16x32_bf16(af, bfr, acc[ct], 0, 0, 0);
    }
    if (ks < 15) {
      bf16x4 va, vb;
      va[0] = f2bf(xa.x); va[1] = f2bf(xa.y); va[2] = f2bf(xa.z); va[3] = f2bf(xa.w);
      vb[0] = f2bf(xb.x); vb[1] = f2bf(xb.y); vb[2] = f2bf(xb.z); vb[3] = f2bf(xb.w);
      *(bf16x4*)(&xs[buf ^ 1][0][sr][sc * 4]) = va;
      *(bf16x4*)(&xs[buf ^ 1][1][sr][sc * 4]) = vb;
    }
    __syncthreads();
  }

  if (h == 1) {
#pragma unroll
    for (int ct = 0; ct < 12; ++ct)
#pragma unroll
      for (int r = 0; r < 4; ++r) part[rs][ct][r][lane] = acc[ct][r];
  }
  __syncthreads();
  if (h == 0) {
#pragma unroll
    for (int ct = 0; ct < 12; ++ct)
#pragma unroll
      for (int r = 0; r < 4; ++r) part[rs][ct][r][lane] += acc[ct][r];
  }
  __syncthreads();

  int b_  = rowbase >> 12;                 // batch
  int srb = rowbase & (SEQ - 1);           // row within batch

  // Qf / Kf fragment-packed stores: thread = (tl, kh, lane)
  {
    int tl  = tid >> 7;
    int kh  = (tid >> 6) & 1;
    int ln  = tid & 63;
    int gg  = ln >> 4;
    int mi2 = ln & 15;
    int tgl = (srb >> 4) + tl;             // tile within batch
    bf16x8 vq, vk;
#pragma unroll
    for (int j = 0; j < 8; ++j) {
      int hd = kh * 32 + 8 * gg + j;
      int ct = hd >> 4, cc = hd & 15;
      int li = (mi2 >> 2) * 16 + cc;
      int r2 = mi2 & 3;
      vq[j] = f2bf(part[tl][ct][r2][li] + bq[hd]);
      vk[j] = f2bf(part[tl][4 + ct][r2][li] + bk[hd]);
    }
    size_t chunk = ((size_t)(b_ * 256 + tgl) * 2 + kh) * 512 + ln * 8;
    *(bf16x8*)(Qf + chunk) = vq;
    *(bf16x8*)(Kf + chunk) = vk;
  }
  // Vf fragment-packed: thread = (ht, lane)
  {
    int ht  = tid >> 6;
    int ln  = tid & 63;
    int gg  = ln >> 4;
    int mi2 = ln & 15;
    int c32 = srb >> 5;
    float bias = bv[ht * 16 + mi2];
    bf16x8 vvv;
#pragma unroll
    for (int hl = 0; hl < 2; ++hl)
#pragma unroll
      for (int j = 0; j < 4; ++j)
        vvv[hl * 4 + j] = f2bf(part[hl][8 + ht][j][gg * 16 + mi2] + bias);
    size_t chunk = ((size_t)(b_ * 128 + c32) * 4 + ht) * 512 + ln * 8;
    *(bf16x8*)(Vf + chunk) = vvv;
  }
}

// ---------------------------------------------------------------------------
// Flash attention: XCD-swizzled (batch = xcd&3 -> K/V L2-resident per XCD),
// all loads fragment-contiguous 1KB, PV via 16x16x16 MFMA straight from
// register P (no LDS P roundtrip). 8 waves/block, pair (t,255-t).
// ---------------------------------------------------------------------------
__global__ __launch_bounds__(512, 4) void attn_kernel(
    const short* __restrict__ Qf, const short* __restrict__ Kf,
    const short* __restrict__ Vf, float* __restrict__ out) {
  __shared__ short lds_o[8][64][17];
  __shared__ float lds_m[8][16];
  __shared__ float lds_l[8][16];

  int tid  = threadIdx.x;
  int w    = tid >> 6;
  int lane = tid & 63;
  int g    = lane >> 4;
  int qi   = lane & 15;

  int bid = blockIdx.x;
  int bb  = bid & 3;                                   // batch = xcd&3
  int jj  = (bid >> 3) + (((bid >> 2) & 1) << 6);      // 0..127

  const float K1 = 0.125f * LOG2E;

  for (int ph = 0; ph < 2; ++ph) {
    int t  = ph ? (255 - jj) : jj;
    int q0 = t * 16;
    int row = q0 + qi;

    const short* qp = Qf + ((size_t)(bb * 256 + t) * 2) * 512 + lane * 8;
    bf16x8 qf0 = *(const bf16x8*)(qp);
    bf16x8 qf1 = *(const bf16x8*)(qp + 512);

    int total64 = (t + 4) >> 2;
    int blo = (w * total64) >> 3;
    int bhi = ((w + 1) * total64) >> 3;

    float m2 = -INFINITY, lsum = 0.f;
    f32x4 o[4];
#pragma unroll
    for (int i = 0; i < 4; ++i) o[i] = (f32x4){0.f, 0.f, 0.f, 0.f};

    for (int b = blo; b < bhi; ++b) {
      int kv0 = b * 64;
      const short* kp = Kf + ((size_t)(bb * 256 + 4 * b) * 2) * 512 + lane * 8;
      const short* vp = Vf + ((size_t)(bb * 128 + 2 * b) * 4) * 512 + lane * 8;

      bf16x8 kfa[4], kfb[4];
#pragma unroll
      for (int c = 0; c < 4; ++c) {
        kfa[c] = *(const bf16x8*)(kp + (c * 2) * 512);
        kfb[c] = *(const bf16x8*)(kp + (c * 2 + 1) * 512);
      }
      bf16x8 vv[8];
#pragma unroll
      for (int i = 0; i < 8; ++i) vv[i] = *(const bf16x8*)(vp + i * 512);

      // ---- QK^T (x32) ----
      f32x4 z[4];
      __builtin_amdgcn_s_setprio(1);
#pragma unroll
      for (int c = 0; c < 4; ++c) {
        f32x4 zz = (f32x4){0.f, 0.f, 0.f, 0.f};
        zz = __builtin_amdgcn_mfma_f32_16x16x32_bf16(kfa[c], qf0, zz, 0, 0, 0);
        zz = __builtin_amdgcn_mfma_f32_16x16x32_bf16(kfb[c], qf1, zz, 0, 0, 0);
        z[c] = zz;
      }
      __builtin_amdgcn_s_setprio(0);

      if (kv0 + 63 > q0) {
#pragma unroll
        for (int c = 0; c < 4; ++c)
#pragma unroll
          for (int r = 0; r < 4; ++r) {
            int col = kv0 + c * 16 + 4 * g + r;
            z[c][r] = (col <= row) ? z[c][r] : -INFINITY;
          }
      }

      // ---- softmax (defer-max THR=8) ----
      float l1 = max3f(z[0][0], z[0][1], z[0][2]);
      float l2 = max3f(z[0][3], z[1][0], z[1][1]);
      float l3 = max3f(z[1][2], z[1][3], z[2][0]);
      float l4 = max3f(z[2][1], z[2][2], z[2][3]);
      float l5 = max3f(z[3][0], z[3][1], z[3][2]);
      float lmax = fmaxf(max3f(l1, l2, l3), max3f(l4, l5, z[3][3]));
      bool grow = __any(fmaf(lmax, K1, -8.0f) > m2);
      if (grow) {
        float gm = fmaxf(lmax, __shfl_xor(lmax, 16));
        gm = fmaxf(gm, __shfl_xor(gm, 32));
        float m2n = fmaxf(m2, gm * K1);
        float alpha = EXP2(m2 - m2n);
        m2 = m2n;
        lsum *= alpha;
#pragma unroll
        for (int i = 0; i < 4; ++i) {
          o[i][0] *= alpha; o[i][1] *= alpha; o[i][2] *= alpha; o[i][3] *= alpha;
        }
      }

      float ls = 0.f;
      bf16x4 pb[4];
#pragma unroll
      for (int c = 0; c < 4; ++c) {
        float p0 = EXP2(fmaf(z[c][0], K1, -m2));
        float p1 = EXP2(fmaf(z[c][1], K1, -m2));
        float p2 = EXP2(fmaf(z[c][2], K1, -m2));
        float p3 = EXP2(fmaf(z[c][3], K1, -m2));
        ls += (p0 + p1) + (p2 + p3);
        pb[c] = pack4(cvtpk(p0, p1), cvtpk(p2, p3));
      }
      lsum += ls;

      // ---- PV (x16, P straight from registers) ----
      __builtin_amdgcn_s_setprio(1);
#pragma unroll
      for (int c = 0; c < 4; ++c) {
        int h2 = c >> 1;
#pragma unroll
        for (int ht = 0; ht < 4; ++ht) {
          bf16x8 vfull = vv[h2 * 4 + ht];
          bf16x4 va = (c & 1) ? __builtin_shufflevector(vfull, vfull, 4, 5, 6, 7)
                              : __builtin_shufflevector(vfull, vfull, 0, 1, 2, 3);
          o[ht] = MFMA16(va, pb[c], o[ht]);
        }
      }
      __builtin_amdgcn_s_setprio(0);
    }

    // ---- cross-wave flash combine ----
    lsum += __shfl_xor(lsum, 16);
    lsum += __shfl_xor(lsum, 32);
#pragma unroll
    for (int ht = 0; ht < 4; ++ht)
#pragma unroll
      for (int r = 0; r < 4; ++r)
        lds_o[w][ht * 16 + 4 * g + r][qi] = f2bf(o[ht][r]);
    if (lane < 16) { lds_m[w][lane] = m2; lds_l[w][lane] = lsum; }
    __syncthreads();

    {
      int q  = tid >> 5;          // 0..15
      int c2 = tid & 31;          // 0..31
      int hb = c2 * 2;
      float mm = lds_m[0][q];
#pragma unroll
      for (int wv = 1; wv < 8; ++wv) mm = fmaxf(mm, lds_m[wv][q]);
      float denom = 0.f, a0 = 0.f, a1 = 0.f;
#pragma unroll
      for (int wv = 0; wv < 8; ++wv) {
        float e = EXP2(lds_m[wv][q] - mm);
        denom += lds_l[wv][q] * e;
        a0 += e * bf2f(lds_o[wv][hb][q]);
        a1 += e * bf2f(lds_o[wv][hb + 1][q]);
      }
      float inv = 1.f / denom;
      float2 res = make_float2(a0 * inv, a1 * inv);
      *(float2*)(out + ((size_t)(bb * SEQ + q0 + q)) * HD + hb) = res;
    }
    __syncthreads();
  }
}

// ---------------------------------------------------------------------------
extern "C" void kernel_launch(void* const* d_in, const int* in_sizes, int n_in,
                              void* d_out, int out_size, void* d_ws, size_t ws_size,
                              hipStream_t stream) {
  const float* X  = (const float*)d_in[0];
  const float* Wq = (const float*)d_in[1];
  const float* bq = (const float*)d_in[2];
  const float* Wk = (const float*)d_in[3];
  const float* bk = (const float*)d_in[4];
  const float* Wv = (const float*)d_in[5];
  const float* bv = (const float*)d_in[6];
  float* out = (float*)d_out;

  char* ws = (char*)d_ws;
  const size_t SZ = (size_t)NROW * HD * 2;
  short* Qf  = (short*)(ws);
  short* Kf  = (short*)(ws + SZ);
  short* Vf  = (short*)(ws + 2 * SZ);
  short* Wtf = (short*)(ws + 3 * SZ);

  wt_kernel<<<48, 256, 0, stream>>>(Wq, Wk, Wv, Wtf);
  qkv_kernel<<<NROW / 32, 256, 0, stream>>>(X, Wtf, bq, bk, bv, Qf, Kf, Vf);
  attn_kernel<<<BATCH * 128, 512, 0, stream>>>(Qf, Kf, Vf, out);
}